// Round 16
// baseline (399.670 us; speedup 1.0000x reference)
//
#include <hip/hip_runtime.h>
#include <hip/hip_bf16.h>

// GAT layer, bucket-sorted edges + LDS-tile accumulation. ~10.6 MB ws, 5 launches,
// zero global atomics:
//   keys = inputs @ W1 + b1            (stored bf16; alphas from f32 accumulator)
//   logit[e] = leaky(a_src[s] + a_dst[d] + a_ee[ty] + b2)
//   attn = exp/segsum ; out[d] = sum attn*(keys[s]+ee[ty])
// R16: killed the CSR regroup + k_out. Buckets are 128 dests; k_fusedout holds
// the bucket's 128x64 f32 output tile in LDS, streams the bucket's edges once
// (exp once/edge), accumulates via ds_add_f32 (padded rows), normalizes, writes.

__device__ __forceinline__ unsigned short f2bf(float f) {
    unsigned u = __float_as_uint(f);
    u += 0x7FFFu + ((u >> 16) & 1u);          // round-nearest-even
    return (unsigned short)(u >> 16);
}
__device__ __forceinline__ float bf2f(unsigned short h) {
    return __uint_as_float(((unsigned)h) << 16);
}

#define NBLK_H 256        // edge chunks for histogram/scatter
#define BSZ    128        // dests per bucket
#define MAXNB  512        // histL/cursor LDS capacity (NB = ceil(N/128) = 391)

// GEMM + alphas + fused bucket histogram (blocks 0..NBLK_H-1 each do one chunk)
__global__ __launch_bounds__(256) void k_nodes(
    const float* __restrict__ inputs, const float* __restrict__ W1,
    const float* __restrict__ b1, const float* __restrict__ W2,
    const float* __restrict__ edge_emb, const int* __restrict__ dst,
    unsigned short* __restrict__ keys, float* __restrict__ alpha_src,
    float* __restrict__ alpha_dst, float* __restrict__ alpha_ee,
    int* __restrict__ histG, int N, int E, int NB, int chunk)
{
    __shared__ float W1s[64 * 64];
    __shared__ float W2s[128];
    __shared__ float xs[16 * 65];
    __shared__ int histL[MAXNB];

    const int t = threadIdx.x;
    const int row0 = blockIdx.x * 16;

    const float4* W1g = reinterpret_cast<const float4*>(W1);
    float4* W1sv = reinterpret_cast<float4*>(W1s);
#pragma unroll
    for (int i = 0; i < 4; i++) W1sv[t + 256 * i] = W1g[t + 256 * i];
    if (t < 128) W2s[t] = W2[t];

#pragma unroll
    for (int i = 0; i < 4; i++) {
        int idx = t + 256 * i;
        int r = idx >> 6, c = idx & 63;
        if (row0 + r < N)
            xs[r * 65 + c] = inputs[(size_t)(row0 + r) * 64 + c];
    }
    __syncthreads();

    const int lane = t & 63;
    const int wave = t >> 6;
    const int rl = wave * 4 + (lane >> 4);
    const int j4 = lane & 15;
    const int row = row0 + rl;

    const float4* W1v = reinterpret_cast<const float4*>(W1s);
    float4 acc = {0.f, 0.f, 0.f, 0.f};
#pragma unroll
    for (int k = 0; k < 64; k++) {
        float a = xs[rl * 65 + k];
        float4 w = W1v[k * 16 + j4];
        acc.x += a * w.x; acc.y += a * w.y; acc.z += a * w.z; acc.w += a * w.w;
    }

    if (row < N) {
        float4 bv = reinterpret_cast<const float4*>(b1)[j4];
        acc.x += bv.x; acc.y += bv.y; acc.z += bv.z; acc.w += bv.w;
        ushort4 kv;
        kv.x = f2bf(acc.x); kv.y = f2bf(acc.y);
        kv.z = f2bf(acc.z); kv.w = f2bf(acc.w);
        reinterpret_cast<ushort4*>(keys)[(size_t)row * 16 + j4] = kv;

        float p1 = acc.x * W2s[4 * j4]      + acc.y * W2s[4 * j4 + 1]
                 + acc.z * W2s[4 * j4 + 2]  + acc.w * W2s[4 * j4 + 3];
        float p2 = acc.x * W2s[64 + 4 * j4]     + acc.y * W2s[64 + 4 * j4 + 1]
                 + acc.z * W2s[64 + 4 * j4 + 2] + acc.w * W2s[64 + 4 * j4 + 3];
#pragma unroll
        for (int m = 8; m >= 1; m >>= 1) {
            p1 += __shfl_xor(p1, m);
            p2 += __shfl_xor(p2, m);
        }
        if (j4 == 0) { alpha_src[row] = p1; alpha_dst[row] = p2; }
    }

    if (blockIdx.x == 0 && t < 6) {
        float s = 0.f;
        for (int c = 0; c < 64; c++) s += edge_emb[t * 64 + c] * W2s[c];
        alpha_ee[t] = s;
    }

    // fused histogram (bucket = dst>>7): blockIdx uniform -> barriers safe
    if (blockIdx.x < NBLK_H) {
        const int blk = blockIdx.x;
        for (int b = t; b < NB; b += 256) histL[b] = 0;
        __syncthreads();
        const int lim = min(E, (blk + 1) * chunk);
        for (int e = blk * chunk + t; e < lim; e += 256)
            atomicAdd(&histL[dst[e] >> 7], 1);
        __syncthreads();
        for (int b = t; b < NB; b += 256)
            histG[b * NBLK_H + blk] = histL[b];
    }
}

// per-bucket row scan: exclusive over the 256 chunk-counts, total -> bsum[b]
__global__ __launch_bounds__(256) void k_scanA(
    int* __restrict__ histG, int* __restrict__ bsum)
{
    __shared__ int sm[256];
    const int t = threadIdx.x;
    const int b = blockIdx.x;
    int v = histG[b * NBLK_H + t];
    sm[t] = v;
    __syncthreads();
    for (int off = 1; off < 256; off <<= 1) {
        int x = 0;
        if (t >= off) x = sm[t - off];
        __syncthreads();
        if (t >= off) sm[t] += x;
        __syncthreads();
    }
    histG[b * NBLK_H + t] = sm[t] - v;     // exclusive
    if (t == 255) bsum[b] = sm[255];
}

// scan bucket totals (NB<=512, 2/thread) -> boff[0..NB], boff[NB] = E
__global__ __launch_bounds__(256) void k_scanB(
    const int* __restrict__ bsum, int* __restrict__ boff, int NB)
{
    __shared__ int sm[256];
    const int t = threadIdx.x;
    int v[2], s = 0;
#pragma unroll
    for (int i = 0; i < 2; i++) {
        int idx = t * 2 + i;
        v[i] = (idx < NB) ? bsum[idx] : 0;
        s += v[i];
    }
    sm[t] = s;
    __syncthreads();
    for (int off = 1; off < 256; off <<= 1) {
        int x = 0;
        if (t >= off) x = sm[t - off];
        __syncthreads();
        if (t >= off) sm[t] += x;
        __syncthreads();
    }
    int run = (t == 0) ? 0 : sm[t - 1];
#pragma unroll
    for (int i = 0; i < 2; i++) {
        int idx = t * 2 + i;
        if (idx < NB) boff[idx] = run;
        run += v[i];
    }
    if (t == 255) boff[NB] = sm[255];
}

// scatter into bucket-sorted order; cursor = boff[b] + row-scanned histG
__global__ __launch_bounds__(256) void k_bucket_scatter(
    const int* __restrict__ src, const int* __restrict__ dst,
    const int* __restrict__ ety, const int* __restrict__ histG,
    const int* __restrict__ boff, int* __restrict__ ebuf,
    int E, int NB, int chunk)
{
    __shared__ int cur[MAXNB];
    const int t = threadIdx.x;
    const int blk = blockIdx.x;
    for (int b = t; b < NB; b += 256) cur[b] = boff[b] + histG[b * NBLK_H + blk];
    __syncthreads();
    const int lim = min(E, (blk + 1) * chunk);
    for (int e = blk * chunk + t; e < lim; e += 256) {
        int d = dst[e];
        int pos = atomicAdd(&cur[d >> 7], 1);
        ebuf[pos] = src[e] | (ety[e] << 16) | ((d & 127) << 19);
    }
}

// one block (512 thr, 8 waves) per bucket: stream edges once, exp once/edge,
// LDS-atomic accumulate into padded outL[128][65] + fsum[128]; normalize; write.
__global__ __launch_bounds__(512) void k_fusedout(
    const int* __restrict__ ebuf, const int* __restrict__ boff,
    const float* __restrict__ a_src, const float* __restrict__ a_dst,
    const float* __restrict__ a_ee, const float* __restrict__ b2,
    const unsigned short* __restrict__ keys, const float* __restrict__ edge_emb,
    float* __restrict__ out, int N)
{
    __shared__ float outL[BSZ * 65];   // padded rows: bank rotation by dl
    __shared__ float fsum[BSZ];
    __shared__ float invL[BSZ];
    __shared__ float baseL[BSZ];
    __shared__ float ee4[384];
    __shared__ float aeeL[8];
    __shared__ int   srec[8][64];
    __shared__ float sw[8][64];

    const int t = threadIdx.x;
    const int b = blockIdx.x;
    const int d0 = b << 7;

    for (int i = t; i < BSZ * 65; i += 512) outL[i] = 0.f;
    for (int i = t; i < 384; i += 512) ee4[i] = edge_emb[i];
    if (t < BSZ) {
        fsum[t] = 0.f;
        baseL[t] = (d0 + t < N) ? (a_dst[d0 + t] + b2[0]) : 0.f;
    }
    if (t < 6) aeeL[t] = a_ee[t];
    __syncthreads();

    const int beg = boff[b], end = boff[b + 1];
    const int lane = t & 63;
    const int wid  = t >> 6;
    const int g    = lane >> 4;
    const int j4   = lane & 15;
    const float4* ee4v = reinterpret_cast<const float4*>(ee4);

    for (int cbase = beg + wid * 64; cbase < end; cbase += 8 * 64) {
        const int n = min(64, end - cbase);
        if (lane < n) {
            int r = ebuf[cbase + lane];
            int dl = (r >> 19) & 127;
            float l = a_src[r & 0xFFFF] + aeeL[(r >> 16) & 7] + baseL[dl];
            l = fmaxf(0.2f * l, l);
            float w = expf(l);
            atomicAdd(&fsum[dl], w);
            srec[wid][lane] = r;
            sw[wid][lane]   = w;
        }
        __builtin_amdgcn_wave_barrier();
        for (int j = g; j < n; j += 4) {
            int   r = srec[wid][j];
            float w = sw[wid][j];
            int s0 = r & 0xFFFF, ty = (r >> 16) & 7, dl = (r >> 19) & 127;
            ushort4 kv = reinterpret_cast<const ushort4*>(keys)[(size_t)s0 * 16 + j4];
            float4  ev = ee4v[ty * 16 + j4];
            float* o = &outL[dl * 65 + j4 * 4];
            atomicAdd(o + 0, (bf2f(kv.x) + ev.x) * w);
            atomicAdd(o + 1, (bf2f(kv.y) + ev.y) * w);
            atomicAdd(o + 2, (bf2f(kv.z) + ev.z) * w);
            atomicAdd(o + 3, (bf2f(kv.w) + ev.w) * w);
        }
        __builtin_amdgcn_wave_barrier();
    }
    __syncthreads();

    if (t < BSZ) invL[t] = (fsum[t] > 0.f) ? 1.f / fsum[t] : 0.f;
    __syncthreads();

    // write 128 dests x 16 float4 (coalesced), guard d < N
    for (int idx = t; idx < BSZ * 16; idx += 512) {
        int dl = idx >> 4, q = idx & 15;
        int d = d0 + dl;
        if (d < N) {
            float iv = invL[dl];
            const float* o = &outL[dl * 65 + q * 4];
            float4 v = { o[0] * iv, o[1] * iv, o[2] * iv, o[3] * iv };
            reinterpret_cast<float4*>(out)[(size_t)d * 16 + q] = v;
        }
    }
}

extern "C" void kernel_launch(void* const* d_in, const int* in_sizes, int n_in,
                              void* d_out, int out_size, void* d_ws, size_t ws_size,
                              hipStream_t stream) {
    const float* inputs   = (const float*)d_in[0];
    const int*   src      = (const int*)d_in[1];
    const int*   dst      = (const int*)d_in[2];
    const int*   ety      = (const int*)d_in[3];
    const float* W1       = (const float*)d_in[5];
    const float* b1       = (const float*)d_in[6];
    const float* W2       = (const float*)d_in[7];
    const float* b2       = (const float*)d_in[8];
    const float* edge_emb = (const float*)d_in[9];
    float* out = (float*)d_out;

    const int N  = in_sizes[0] / 64;
    const int E  = in_sizes[1];
    const int NB = (N + BSZ - 1) / BSZ;     // 391 buckets of 128 dests
    const int M  = NB * NBLK_H;             // histG length (bucket-major)
    const int chunk = (E + NBLK_H - 1) / NBLK_H;

    // workspace layout in 4-byte units; total ~10.6 MB
    float*          ws      = (float*)d_ws;
    unsigned short* keys    = (unsigned short*)ws;          // N*64 bf16 = N*32 ints
    float*          a_src   = ws + (size_t)N * 32;          // N
    float*          a_dst   = a_src + N;                    // N
    float*          a_ee    = a_dst + N;                    // 8
    int*            histG   = (int*)(a_ee + 8);             // M
    int*            bsum    = histG + M;                    // 512
    int*            boff    = bsum + 512;                   // NB+1 (pad 512)
    int*            ebuf    = boff + 512;                   // E

    int nblk = (N + 15) / 16;
    k_nodes<<<nblk, 256, 0, stream>>>(inputs, W1, b1, W2, edge_emb, dst,
                                      keys, a_src, a_dst, a_ee, histG, N, E, NB, chunk);
    k_scanA<<<NB, 256, 0, stream>>>(histG, bsum);
    k_scanB<<<1, 256, 0, stream>>>(bsum, boff, NB);
    k_bucket_scatter<<<NBLK_H, 256, 0, stream>>>(src, dst, ety, histG,
                                                 boff, ebuf, E, NB, chunk);
    k_fusedout<<<NB, 512, 0, stream>>>(ebuf, boff, a_src, a_dst, a_ee, b2,
                                       keys, edge_emb, out, N);
}

// Round 17
// 83.138 us; speedup vs baseline: 4.8073x; 4.8073x over previous
//
#include <hip/hip_runtime.h>
#include <hip/hip_bf16.h>
#include <hip/hip_fp16.h>

// GAT layer, CSR-by-destination (R15 structure), ~12.2 MB ws, zero global atomics,
// 5 launches:
//   keys = inputs @ W1 + b1            (stored bf16; alphas from f32 accumulator)
//   logit[e] = leaky(a_src[s] + a_dst[d] + a_ee[ty] + b2)
//   attn = exp/segsum ; out[d] = sum attn*(keys[s]+ee[ty])
// R16 lesson (REVERTED): LDS-tile accumulate = 64 scalar ds_add RMW/edge -> 365us.
// Sort-then-register-accumulate is the right structure.
// R17 deltas vs R15: k_scanB eliminated (boff derived from bsum by LDS scan in
// consumers); k_out group loop unrolled x2 (dual gathers in flight).

__device__ __forceinline__ unsigned short f2bf(float f) {
    unsigned u = __float_as_uint(f);
    u += 0x7FFFu + ((u >> 16) & 1u);          // round-nearest-even
    return (unsigned short)(u >> 16);
}
__device__ __forceinline__ float bf2f(unsigned short h) {
    return __uint_as_float(((unsigned)h) << 16);
}

#define NBLK_H 256        // edge chunks for histogram/scatter
#define CAPB   16384      // LDS edge-stage capacity per bucket (4x statistical max)

// GEMM + alphas + fused bucket histogram (blocks 0..NBLK_H-1 each do one chunk)
__global__ __launch_bounds__(256) void k_nodes(
    const float* __restrict__ inputs, const float* __restrict__ W1,
    const float* __restrict__ b1, const float* __restrict__ W2,
    const float* __restrict__ edge_emb, const int* __restrict__ dst,
    unsigned short* __restrict__ keys, float* __restrict__ alpha_src,
    float* __restrict__ alpha_dst, float* __restrict__ alpha_ee,
    int* __restrict__ histG, int N, int E, int NB, int chunk)
{
    __shared__ float W1s[64 * 64];
    __shared__ float W2s[128];
    __shared__ float xs[16 * 65];
    __shared__ int histL[256];

    const int t = threadIdx.x;
    const int row0 = blockIdx.x * 16;

    const float4* W1g = reinterpret_cast<const float4*>(W1);
    float4* W1sv = reinterpret_cast<float4*>(W1s);
#pragma unroll
    for (int i = 0; i < 4; i++) W1sv[t + 256 * i] = W1g[t + 256 * i];
    if (t < 128) W2s[t] = W2[t];

#pragma unroll
    for (int i = 0; i < 4; i++) {
        int idx = t + 256 * i;
        int r = idx >> 6, c = idx & 63;
        if (row0 + r < N)
            xs[r * 65 + c] = inputs[(size_t)(row0 + r) * 64 + c];
    }
    __syncthreads();

    const int lane = t & 63;
    const int wave = t >> 6;
    const int rl = wave * 4 + (lane >> 4);
    const int j4 = lane & 15;
    const int row = row0 + rl;

    const float4* W1v = reinterpret_cast<const float4*>(W1s);
    float4 acc = {0.f, 0.f, 0.f, 0.f};
#pragma unroll
    for (int k = 0; k < 64; k++) {
        float a = xs[rl * 65 + k];
        float4 w = W1v[k * 16 + j4];
        acc.x += a * w.x; acc.y += a * w.y; acc.z += a * w.z; acc.w += a * w.w;
    }

    if (row < N) {
        float4 bv = reinterpret_cast<const float4*>(b1)[j4];
        acc.x += bv.x; acc.y += bv.y; acc.z += bv.z; acc.w += bv.w;
        ushort4 kv;
        kv.x = f2bf(acc.x); kv.y = f2bf(acc.y);
        kv.z = f2bf(acc.z); kv.w = f2bf(acc.w);
        reinterpret_cast<ushort4*>(keys)[(size_t)row * 16 + j4] = kv;

        float p1 = acc.x * W2s[4 * j4]      + acc.y * W2s[4 * j4 + 1]
                 + acc.z * W2s[4 * j4 + 2]  + acc.w * W2s[4 * j4 + 3];
        float p2 = acc.x * W2s[64 + 4 * j4]     + acc.y * W2s[64 + 4 * j4 + 1]
                 + acc.z * W2s[64 + 4 * j4 + 2] + acc.w * W2s[64 + 4 * j4 + 3];
#pragma unroll
        for (int m = 8; m >= 1; m >>= 1) {
            p1 += __shfl_xor(p1, m);
            p2 += __shfl_xor(p2, m);
        }
        if (j4 == 0) { alpha_src[row] = p1; alpha_dst[row] = p2; }
    }

    if (blockIdx.x == 0 && t < 6) {
        float s = 0.f;
        for (int c = 0; c < 64; c++) s += edge_emb[t * 64 + c] * W2s[c];
        alpha_ee[t] = s;
    }

    // fused histogram (bucket = dst>>8): blockIdx uniform -> barriers safe
    if (blockIdx.x < NBLK_H) {
        const int blk = blockIdx.x;
        for (int b = t; b < NB; b += 256) histL[b] = 0;
        __syncthreads();
        const int lim = min(E, (blk + 1) * chunk);
        for (int e = blk * chunk + t; e < lim; e += 256)
            atomicAdd(&histL[dst[e] >> 8], 1);
        __syncthreads();
        for (int b = t; b < NB; b += 256)
            histG[b * NBLK_H + blk] = histL[b];
    }
}

// per-bucket row scan: exclusive over the 256 chunk-counts, total -> bsum[b]
__global__ __launch_bounds__(256) void k_scanA(
    int* __restrict__ histG, int* __restrict__ bsum)
{
    __shared__ int sm[256];
    const int t = threadIdx.x;
    const int b = blockIdx.x;
    int v = histG[b * NBLK_H + t];
    sm[t] = v;
    __syncthreads();
    for (int off = 1; off < 256; off <<= 1) {
        int x = 0;
        if (t >= off) x = sm[t - off];
        __syncthreads();
        if (t >= off) sm[t] += x;
        __syncthreads();
    }
    histG[b * NBLK_H + t] = sm[t] - v;     // exclusive
    if (t == 255) bsum[b] = sm[255];
}

// scatter into bucket-sorted order; boff derived locally from bsum (LDS scan)
__global__ __launch_bounds__(256) void k_bucket_scatter(
    const int* __restrict__ src, const int* __restrict__ dst,
    const int* __restrict__ ety, const int* __restrict__ histG,
    const int* __restrict__ bsum, int* __restrict__ ebuf,
    int E, int NB, int chunk)
{
    __shared__ int sm[256];
    __shared__ int cur[256];
    const int t = threadIdx.x;
    const int blk = blockIdx.x;

    int bs = (t < NB) ? bsum[t] : 0;
    sm[t] = bs;
    __syncthreads();
    for (int off = 1; off < 256; off <<= 1) {
        int x = 0;
        if (t >= off) x = sm[t - off];
        __syncthreads();
        if (t >= off) sm[t] += x;
        __syncthreads();
    }
    if (t < NB) cur[t] = (sm[t] - bs) + histG[t * NBLK_H + blk];  // boff[t] + chunk offset
    __syncthreads();

    const int lim = min(E, (blk + 1) * chunk);
    for (int e = blk * chunk + t; e < lim; e += 256) {
        int d = dst[e];
        int pos = atomicAdd(&cur[d >> 8], 1);
        ebuf[pos] = src[e] | (ety[e] << 16) | ((d & 255) << 19);
    }
}

// one block per bucket: stage edges in LDS, 256-way sub-histogram + scan,
// write row_ptr, regroup in-place by dest, compute exp ONCE per edge ->
// wexp f16 (coalesced) + per-dest dsum via LDS float atomics.
// boff derived locally from bsum scan.
__global__ __launch_bounds__(256) void k_localcsr(
    int* __restrict__ ebuf, const int* __restrict__ bsum,
    const float* __restrict__ a_src, const float* __restrict__ a_dst,
    const float* __restrict__ a_ee, const float* __restrict__ b2,
    int* __restrict__ rp, __half* __restrict__ wexp,
    float* __restrict__ dsum, int N, int NB, int E)
{
    __shared__ int   estage[CAPB];
    __shared__ int   h[256];
    __shared__ int   sm[256];
    __shared__ int   cur2[256];
    __shared__ float fsum[256];
    __shared__ float baseL[256];
    __shared__ float aeeL[8];

    const int t = threadIdx.x;
    const int b = blockIdx.x;
    const int idx = (b << 8) + t;

    // derive begB/endB from bsum scan (inclusive scan in sm)
    int bs = (t < NB) ? bsum[t] : 0;
    sm[t] = bs;
    __syncthreads();
    for (int off = 1; off < 256; off <<= 1) {
        int x = 0;
        if (t >= off) x = sm[t - off];
        __syncthreads();
        if (t >= off) sm[t] += x;
        __syncthreads();
    }
    const int begB = (b == 0) ? 0 : sm[b - 1];
    const int endB = sm[b];
    const int cnt  = endB - begB;
    __syncthreads();

    h[t] = 0;
    fsum[t] = 0.f;
    baseL[t] = (idx < N) ? (a_dst[idx] + b2[0]) : 0.f;
    if (t < 6) aeeL[t] = a_ee[t];
    __syncthreads();

    for (int i = t; i < cnt; i += 256) {
        int r = ebuf[begB + i];
        if (i < CAPB) estage[i] = r;
        atomicAdd(&h[(r >> 19) & 255], 1);
    }
    __syncthreads();

    sm[t] = h[t];
    __syncthreads();
    for (int off = 1; off < 256; off <<= 1) {
        int x = 0;
        if (t >= off) x = sm[t - off];
        __syncthreads();
        if (t >= off) sm[t] += x;
        __syncthreads();
    }
    int lstart = (t == 0) ? 0 : sm[t - 1];

    if (idx < N) rp[idx] = begB + lstart;
    if (b == NB - 1 && t == 0) rp[N] = E;
    cur2[t] = begB + lstart;
    __syncthreads();

    for (int i = t; i < cnt; i += 256) {
        int r = (i < CAPB) ? estage[i] : ebuf[begB + i];
        int s  = r & 0xFFFF;
        int ty = (r >> 16) & 7;
        int dl = (r >> 19) & 255;
        float l = a_src[s] + aeeL[ty] + baseL[dl];
        l = fmaxf(0.2f * l, l);
        float w = expf(l);
        int pos = atomicAdd(&cur2[dl], 1);
        ebuf[pos] = r & 0x7FFFF;               // src | ty<<16
        wexp[pos] = __float2half_rn(w);
        atomicAdd(&fsum[dl], w);
    }
    __syncthreads();
    if (idx < N) dsum[idx] = fsum[t];
}

// one 64-lane wave per destination; exp-free single pass.
// stage 64 (rec,w) in LDS; 4x16-lane groups; group loop unrolled x2 (dual
// gathers in flight); inv applied once at the end.
__global__ __launch_bounds__(256) void k_out(
    const int* __restrict__ rp, const int* __restrict__ erec,
    const __half* __restrict__ wexp, const float* __restrict__ dsum,
    const unsigned short* __restrict__ keys, const float* __restrict__ edge_emb,
    float* __restrict__ out, int N)
{
    __shared__ float ee4[384];
    __shared__ int   srec[4][64];
    __shared__ float sw[4][64];

    const int t = threadIdx.x;
    for (int i = t; i < 384; i += 256) ee4[i] = edge_emb[i];
    __syncthreads();

    const int lane = t & 63;
    const int wid  = t >> 6;
    const int d = blockIdx.x * 4 + wid;
    if (d >= N) return;

    const int beg = rp[d], end = rp[d + 1];
    const float inv = (end > beg) ? 1.f / dsum[d] : 0.f;

    const int g  = lane >> 4;
    const int j4 = lane & 15;
    const float4* ee4v = reinterpret_cast<const float4*>(ee4);
    float4 acc0 = {0.f, 0.f, 0.f, 0.f};
    float4 acc1 = {0.f, 0.f, 0.f, 0.f};

    for (int cbase = beg; cbase < end; cbase += 64) {
        const int n = min(64, end - cbase);
        if (lane < n) {
            srec[wid][lane] = erec[cbase + lane];
            sw[wid][lane]   = __half2float(wexp[cbase + lane]);
        }
        __builtin_amdgcn_wave_barrier();
        int j = g;
        for (; j + 4 < n; j += 8) {
            int   r0 = srec[wid][j];
            int   r1 = srec[wid][j + 4];
            float w0 = sw[wid][j];
            float w1 = sw[wid][j + 4];
            int sA = r0 & 0xFFFF, tyA = r0 >> 16;
            int sB = r1 & 0xFFFF, tyB = r1 >> 16;
            ushort4 kv0 = reinterpret_cast<const ushort4*>(keys)[(size_t)sA * 16 + j4];
            ushort4 kv1 = reinterpret_cast<const ushort4*>(keys)[(size_t)sB * 16 + j4];
            float4  ev0 = ee4v[tyA * 16 + j4];
            float4  ev1 = ee4v[tyB * 16 + j4];
            acc0.x += (bf2f(kv0.x) + ev0.x) * w0;
            acc0.y += (bf2f(kv0.y) + ev0.y) * w0;
            acc0.z += (bf2f(kv0.z) + ev0.z) * w0;
            acc0.w += (bf2f(kv0.w) + ev0.w) * w0;
            acc1.x += (bf2f(kv1.x) + ev1.x) * w1;
            acc1.y += (bf2f(kv1.y) + ev1.y) * w1;
            acc1.z += (bf2f(kv1.z) + ev1.z) * w1;
            acc1.w += (bf2f(kv1.w) + ev1.w) * w1;
        }
        if (j < n) {
            int   r0 = srec[wid][j];
            float w0 = sw[wid][j];
            int sA = r0 & 0xFFFF, tyA = r0 >> 16;
            ushort4 kv0 = reinterpret_cast<const ushort4*>(keys)[(size_t)sA * 16 + j4];
            float4  ev0 = ee4v[tyA * 16 + j4];
            acc0.x += (bf2f(kv0.x) + ev0.x) * w0;
            acc0.y += (bf2f(kv0.y) + ev0.y) * w0;
            acc0.z += (bf2f(kv0.z) + ev0.z) * w0;
            acc0.w += (bf2f(kv0.w) + ev0.w) * w0;
        }
        __builtin_amdgcn_wave_barrier();
    }

    float4 acc = { acc0.x + acc1.x, acc0.y + acc1.y,
                   acc0.z + acc1.z, acc0.w + acc1.w };
#pragma unroll
    for (int m = 16; m <= 32; m <<= 1) {
        acc.x += __shfl_xor(acc.x, m);
        acc.y += __shfl_xor(acc.y, m);
        acc.z += __shfl_xor(acc.z, m);
        acc.w += __shfl_xor(acc.w, m);
    }
    if (g == 0) {
        acc.x *= inv; acc.y *= inv; acc.z *= inv; acc.w *= inv;
        reinterpret_cast<float4*>(out)[(size_t)d * 16 + j4] = acc;
    }
}

extern "C" void kernel_launch(void* const* d_in, const int* in_sizes, int n_in,
                              void* d_out, int out_size, void* d_ws, size_t ws_size,
                              hipStream_t stream) {
    const float* inputs   = (const float*)d_in[0];
    const int*   src      = (const int*)d_in[1];
    const int*   dst      = (const int*)d_in[2];
    const int*   ety      = (const int*)d_in[3];
    const float* W1       = (const float*)d_in[5];
    const float* b1       = (const float*)d_in[6];
    const float* W2       = (const float*)d_in[7];
    const float* b2       = (const float*)d_in[8];
    const float* edge_emb = (const float*)d_in[9];
    float* out = (float*)d_out;

    const int N  = in_sizes[0] / 64;
    const int E  = in_sizes[1];
    const int NB = (N + 255) >> 8;          // 196 buckets of 256 dests
    const int M  = NB * NBLK_H;             // histG length (bucket-major)
    const int chunk = (E + NBLK_H - 1) / NBLK_H;

    // workspace layout in 4-byte units; total ~12.2 MB
    float*          ws      = (float*)d_ws;
    unsigned short* keys    = (unsigned short*)ws;          // N*64 bf16 = N*32 ints
    float*          a_src   = ws + (size_t)N * 32;          // N
    float*          a_dst   = a_src + N;                    // N
    float*          a_ee    = a_dst + N;                    // 8
    int*            rp      = (int*)(a_ee + 8);             // N+2
    int*            histG   = rp + (N + 2);                 // M
    int*            bsum    = histG + M;                    // 256
    int*            ebuf    = bsum + 256;                   // E
    __half*         wexp    = (__half*)(ebuf + E);          // E halves
    float*          dsum    = (float*)(wexp + ((E + 1) & ~1)); // N

    int nblk = (N + 15) / 16;
    k_nodes<<<nblk, 256, 0, stream>>>(inputs, W1, b1, W2, edge_emb, dst,
                                      keys, a_src, a_dst, a_ee, histG, N, E, NB, chunk);
    k_scanA<<<NB, 256, 0, stream>>>(histG, bsum);
    k_bucket_scatter<<<NBLK_H, 256, 0, stream>>>(src, dst, ety, histG,
                                                 bsum, ebuf, E, NB, chunk);
    k_localcsr<<<NB, 256, 0, stream>>>(ebuf, bsum, a_src, a_dst, a_ee, b2,
                                       rp, wexp, dsum, N, NB, E);
    k_out<<<(N + 3) / 4, 256, 0, stream>>>(rp, ebuf, wexp, dsum, keys, edge_emb, out, N);
}